// Round 1
// baseline (1193.569 us; speedup 1.0000x reference)
//
#include <hip/hip_runtime.h>
#include <cstdint>
#include <cstddef>

#define NB   16
#define NC   256
#define NPIX 3136
#define NW   56
#define EPSV 1e-5f

// ws layout in floats
#define OFF_A    0u        // A[384][256]  (Wall^T, row = out channel)
#define OFF_BNA  98304u    // [384]
#define OFF_BNB  98688u    // [384]
#define OFF_WRE  99072u    // wre[225][4][16]
#define OFF_LC   113472u   // Lc[16][16][64]
#define OFF_Y    131072u   // Y[16][384][3136]  (q:0..63, k:64..127, v:128..383)

// ---------------- prep: build A, BN coeffs, reorder pos_w, zero Lc -------------
__global__ void prep_kernel(const float* __restrict__ Wq, const float* __restrict__ Wk,
                            const float* __restrict__ Wv, const float* __restrict__ pos_w,
                            const float* __restrict__ gq, const float* __restrict__ bq,
                            const float* __restrict__ mq, const float* __restrict__ vq,
                            const float* __restrict__ gv, const float* __restrict__ bv,
                            const float* __restrict__ mv, const float* __restrict__ vv,
                            float* __restrict__ ws) {
  int d = blockIdx.x;    // 0..383
  int c = threadIdx.x;   // 0..255
  float w;
  if (d < 64)        w = Wq[c * 64 + d];
  else if (d < 128)  w = Wk[c * 64 + (d - 64)];
  else               w = Wv[c * 256 + (d - 128)];
  ws[OFF_A + d * 256 + c] = w;
  if (c == 0) {
    float sa, sb;
    if (d < 64)        { float inv = gq[d] / sqrtf(vq[d] + EPSV); sa = inv; sb = bq[d] - mq[d] * inv; }
    else if (d < 128)  { sa = 1.0f; sb = 0.0f; }
    else               { int j = d - 128; float inv = gv[j] / sqrtf(vv[j] + EPSV); sa = inv; sb = bv[j] - mv[j] * inv; }
    ws[OFF_BNA + d] = sa;
    ws[OFF_BNB + d] = sb;
  }
  int i = d * 256 + c;
  if (i < 14400) {  // wre[del][u][k] = pos_w[k][u][del]
    int del = i >> 6, rem = i & 63, u = rem >> 4, k = rem & 15;
    ws[OFF_WRE + i] = pos_w[k * 900 + u * 225 + del];
  }
  if (d < 64) ws[OFF_LC + i] = 0.0f;  // 16384 floats
}

// ---------------- stage 1: QKV projection GEMM + BN ---------------------------
// Y[b][d][n] = bnA[d] * sum_c A[d][c] * x[b][c][n] + bnB[d]
__launch_bounds__(256, 2)
__global__ void qkv_gemm(const float* __restrict__ x, const float* __restrict__ wsc,
                         float* __restrict__ Y) {
  __shared__ float As[64 * 33];
  __shared__ float Xs[32 * 64];
  const float* A   = wsc + OFF_A;
  const float* bnA = wsc + OFF_BNA;
  const float* bnB = wsc + OFF_BNB;
  int t  = threadIdx.x;
  int n0 = blockIdx.x * 64, d0 = blockIdx.y * 64, b = blockIdx.z;
  int td = t >> 4, tn = t & 15;
  float acc[4][4];
#pragma unroll
  for (int i = 0; i < 4; ++i)
#pragma unroll
    for (int j = 0; j < 4; ++j) acc[i][j] = 0.0f;
  const size_t xbase = (size_t)b * NC * NPIX;
  for (int kt = 0; kt < 8; ++kt) {
    int k0 = kt * 32;
    // stage A tile [64 rows d][32 cols c]
    const float* ag = A + (d0 + (t >> 2)) * 256 + k0 + (t & 3) * 8;
    float4 a0 = *(const float4*)(ag);
    float4 a1 = *(const float4*)(ag + 4);
    // stage X tile [32 rows c][64 cols n]
    const float* xg = x + xbase + (size_t)(k0 + (t >> 3)) * NPIX + n0 + (t & 7) * 8;
    float4 b0 = *(const float4*)(xg);
    float4 b1 = *(const float4*)(xg + 4);
    float* ap = As + (t >> 2) * 33 + (t & 3) * 8;
    ap[0] = a0.x; ap[1] = a0.y; ap[2] = a0.z; ap[3] = a0.w;
    ap[4] = a1.x; ap[5] = a1.y; ap[6] = a1.z; ap[7] = a1.w;
    *(float4*)(Xs + (t >> 3) * 64 + (t & 7) * 8)     = b0;
    *(float4*)(Xs + (t >> 3) * 64 + (t & 7) * 8 + 4) = b1;
    __syncthreads();
#pragma unroll 8
    for (int kk = 0; kk < 32; ++kk) {
      float av[4];
#pragma unroll
      for (int i = 0; i < 4; ++i) av[i] = As[(td * 4 + i) * 33 + kk];
      float4 xv = *(const float4*)(Xs + kk * 64 + tn * 4);
#pragma unroll
      for (int i = 0; i < 4; ++i) {
        acc[i][0] = fmaf(av[i], xv.x, acc[i][0]);
        acc[i][1] = fmaf(av[i], xv.y, acc[i][1]);
        acc[i][2] = fmaf(av[i], xv.z, acc[i][2]);
        acc[i][3] = fmaf(av[i], xv.w, acc[i][3]);
      }
    }
    __syncthreads();
  }
#pragma unroll
  for (int i = 0; i < 4; ++i) {
    int d = d0 + td * 4 + i;
    float sa = bnA[d], sb = bnB[d];
    float4 o;
    o.x = fmaf(acc[i][0], sa, sb);
    o.y = fmaf(acc[i][1], sa, sb);
    o.z = fmaf(acc[i][2], sa, sb);
    o.w = fmaf(acc[i][3], sa, sb);
    *(float4*)(Y + ((size_t)b * 384 + d) * NPIX + n0 + tn * 4) = o;
  }
}

// ---------------- stage 2: softmax over positions for k rows ------------------
__global__ void softmax_k(float* __restrict__ Y) {
  int row = blockIdx.x;           // 0..1023 = b*64 + (u*16+k)
  int b = row >> 6, r = row & 63;
  float* p = Y + ((size_t)b * 384 + 64 + r) * NPIX;
  int t = threadIdx.x;
  __shared__ float red[8];
  float m = -3.4e38f;
  for (int n = t; n < NPIX; n += 256) m = fmaxf(m, p[n]);
#pragma unroll
  for (int off = 32; off; off >>= 1) m = fmaxf(m, __shfl_xor(m, off, 64));
  if ((t & 63) == 0) red[t >> 6] = m;
  __syncthreads();
  if (t == 0) red[0] = fmaxf(fmaxf(red[0], red[1]), fmaxf(red[2], red[3]));
  __syncthreads();
  m = red[0];
  float s = 0.0f;
  for (int n = t; n < NPIX; n += 256) { float e = __expf(p[n] - m); p[n] = e; s += e; }
#pragma unroll
  for (int off = 32; off; off >>= 1) s += __shfl_xor(s, off, 64);
  if ((t & 63) == 0) red[4 + (t >> 6)] = s;
  __syncthreads();
  if (t == 0) red[4] = red[4] + red[5] + red[6] + red[7];
  __syncthreads();
  float inv = 1.0f / red[4];
  for (int n = t; n < NPIX; n += 256) p[n] *= inv;
}

// ---------------- stage 3: Lc[b][k][v] = sum_{u,n} ksm[b,u,k,n] * v[b,u,v,n] --
__global__ void lc_kernel(const float* __restrict__ Y, float* __restrict__ ws) {
  int v = blockIdx.x, u = blockIdx.y, b = blockIdx.z;
  float* Lc = ws + OFF_LC;
  const float* krows = Y + ((size_t)b * 384 + 64 + u * 16) * NPIX;
  const float* vrow  = Y + ((size_t)b * 384 + 128 + u * 64 + v) * NPIX;
  float acc[16];
#pragma unroll
  for (int k = 0; k < 16; ++k) acc[k] = 0.0f;
  for (int n = threadIdx.x; n < NPIX; n += 256) {
    float vv = vrow[n];
#pragma unroll
    for (int k = 0; k < 16; ++k) acc[k] = fmaf(krows[(size_t)k * NPIX + n], vv, acc[k]);
  }
#pragma unroll
  for (int k = 0; k < 16; ++k) {
    float a = acc[k];
#pragma unroll
    for (int off = 32; off; off >>= 1) a += __shfl_xor(a, off, 64);
    if ((threadIdx.x & 63) == 0) atomicAdd(&Lc[(b * 16 + k) * 64 + v], a);
  }
}

// ---------------- stage 4: position conv + fused output contraction -----------
// out[b][h*64+v][n] = sum_k q[b,h,k,n] * ( pos_b[k] + Lc[b,k,v] + conv(v)[k,v,n] )
__launch_bounds__(256)
__global__ void pos_lambda(const float* __restrict__ Y, const float* __restrict__ wsc,
                           const float* __restrict__ pos_b, float* __restrict__ out) {
  // grid: (7 row-tiles of 8, v=64, b=16); tile = 8 rows x 56 cols, halo 22 x 70
  __shared__ float vt[4 * 22 * 70];  // 6160 floats = 24.6 KB
  int tr = blockIdx.x, v = blockIdx.y, b = blockIdx.z;
  int r0 = tr * 8;
  int t = threadIdx.x;
  const float* wre = wsc + OFF_WRE;
  const float* Lc  = wsc + OFF_LC;
  // load v halo (zero-padded)
  for (int i = t; i < 6160; i += 256) {
    int u = i / 1540, rem = i % 1540, rr = rem / 70, cc = rem % 70;
    int gr = r0 - 7 + rr, gc = cc - 7;
    float val = 0.0f;
    if (gr >= 0 && gr < NW && gc >= 0 && gc < NW)
      val = Y[((size_t)b * 384 + 128 + u * 64 + v) * NPIX + gr * NW + gc];
    vt[i] = val;
  }
  __syncthreads();
  if (t < 224) {
    int pr = t / 56, pc = t % 56;   // rows r0+pr and r0+pr+4
    float m0[16], m1[16];
#pragma unroll
    for (int k = 0; k < 16; ++k) {
      float init = pos_b[k] + Lc[(b * 16 + k) * 64 + v];
      m0[k] = init; m1[k] = init;
    }
#pragma unroll 1
    for (int u = 0; u < 4; ++u) {
#pragma unroll 1
      for (int dh = 0; dh < 15; ++dh) {
        const float* vr0 = vt + u * 1540 + (pr + dh) * 70 + pc;
        const float* vr1 = vr0 + 280;  // +4 rows
        const float* wrow = wre + (dh * 15) * 64 + u * 16;
#pragma unroll
        for (int dw = 0; dw < 15; ++dw) {
          float v0 = vr0[dw], v1 = vr1[dw];
          const float4* w4 = (const float4*)(wrow + dw * 64);
#pragma unroll
          for (int kq = 0; kq < 4; ++kq) {
            float4 w = w4[kq];
            m0[kq * 4 + 0] = fmaf(w.x, v0, m0[kq * 4 + 0]);
            m0[kq * 4 + 1] = fmaf(w.y, v0, m0[kq * 4 + 1]);
            m0[kq * 4 + 2] = fmaf(w.z, v0, m0[kq * 4 + 2]);
            m0[kq * 4 + 3] = fmaf(w.w, v0, m0[kq * 4 + 3]);
            m1[kq * 4 + 0] = fmaf(w.x, v1, m1[kq * 4 + 0]);
            m1[kq * 4 + 1] = fmaf(w.y, v1, m1[kq * 4 + 1]);
            m1[kq * 4 + 2] = fmaf(w.z, v1, m1[kq * 4 + 2]);
            m1[kq * 4 + 3] = fmaf(w.w, v1, m1[kq * 4 + 3]);
          }
        }
      }
    }
    int n  = (r0 + pr) * NW + pc;
    int n2 = n + 4 * NW;
#pragma unroll
    for (int h = 0; h < 4; ++h) {
      float y0 = 0.0f, y1 = 0.0f;
#pragma unroll
      for (int k = 0; k < 16; ++k) {
        const float* qrow = Y + ((size_t)b * 384 + h * 16 + k) * NPIX;
        y0 = fmaf(qrow[n],  m0[k], y0);
        y1 = fmaf(qrow[n2], m1[k], y1);
      }
      out[((size_t)b * 256 + h * 64 + v) * NPIX + n]  = y0;
      out[((size_t)b * 256 + h * 64 + v) * NPIX + n2] = y1;
    }
  }
}

extern "C" void kernel_launch(void* const* d_in, const int* in_sizes, int n_in,
                              void* d_out, int out_size, void* d_ws, size_t ws_size,
                              hipStream_t stream) {
  const float* x     = (const float*)d_in[0];
  const float* Wq    = (const float*)d_in[1];
  const float* Wk    = (const float*)d_in[2];
  const float* Wv    = (const float*)d_in[3];
  const float* pos_w = (const float*)d_in[4];
  const float* pos_b = (const float*)d_in[5];
  const float* gq    = (const float*)d_in[6];
  const float* bq    = (const float*)d_in[7];
  const float* mq    = (const float*)d_in[8];
  const float* vq    = (const float*)d_in[9];
  const float* gv    = (const float*)d_in[10];
  const float* bv    = (const float*)d_in[11];
  const float* mv    = (const float*)d_in[12];
  const float* vv    = (const float*)d_in[13];
  float* ws  = (float*)d_ws;
  float* out = (float*)d_out;
  float* Y   = ws + OFF_Y;

  prep_kernel<<<dim3(384), 256, 0, stream>>>(Wq, Wk, Wv, pos_w, gq, bq, mq, vq,
                                             gv, bv, mv, vv, ws);
  qkv_gemm<<<dim3(49, 6, 16), 256, 0, stream>>>(x, ws, Y);
  softmax_k<<<dim3(1024), 256, 0, stream>>>(Y);
  lc_kernel<<<dim3(64, 4, 16), 256, 0, stream>>>(Y, ws);
  pos_lambda<<<dim3(7, 64, 16), 256, 0, stream>>>(Y, ws, pos_b, out);
}

// Round 2
// 549.693 us; speedup vs baseline: 2.1713x; 2.1713x over previous
//
#include <hip/hip_runtime.h>
#include <cstdint>
#include <cstddef>

#define NB   16
#define NC   256
#define NPIX 3136
#define NW   56
#define EPSV 1e-5f

// ws layout in floats
#define OFF_A    0u        // A[384][256]
#define OFF_BNA  98304u    // [384]
#define OFF_BNB  98688u    // [384]
#define OFF_WT   99072u    // wtab: 30 chunks x 64 lanes x 4 dwords (8 bf16) = 7680 dwords
#define OFF_LC   113472u   // Lc[16][16][64]
#define OFF_Y    131072u   // Y[16][384][3136]; per-b rows 0..31 reused as qb (bf16 pairs)

typedef short bf16x8 __attribute__((ext_vector_type(8)));
typedef float f32x4  __attribute__((ext_vector_type(4)));

__device__ __forceinline__ uint32_t f2bf(float f) {
  uint32_t x = __float_as_uint(f);
  uint32_t r = x + 0x7fffu + ((x >> 16) & 1u);
  return r >> 16;
}

// ---------------- prep: build A, BN coeffs, MFMA weight fragments, zero Lc ----
__global__ void prep_kernel(const float* __restrict__ Wq, const float* __restrict__ Wk,
                            const float* __restrict__ Wv, const float* __restrict__ pos_w,
                            const float* __restrict__ gq, const float* __restrict__ bq,
                            const float* __restrict__ mq, const float* __restrict__ vq,
                            const float* __restrict__ gv, const float* __restrict__ bv,
                            const float* __restrict__ mv, const float* __restrict__ vv,
                            float* __restrict__ ws) {
  int d = blockIdx.x;    // 0..383
  int c = threadIdx.x;   // 0..255
  float w;
  if (d < 64)        w = Wq[c * 64 + d];
  else if (d < 128)  w = Wk[c * 64 + (d - 64)];
  else               w = Wv[c * 256 + (d - 128)];
  ws[OFF_A + d * 256 + c] = w;
  if (c == 0) {
    float sa, sb;
    if (d < 64)        { float inv = gq[d] / sqrtf(vq[d] + EPSV); sa = inv; sb = bq[d] - mq[d] * inv; }
    else if (d < 128)  { sa = 1.0f; sb = 0.0f; }
    else               { int j = d - 128; float inv = gv[j] / sqrtf(vv[j] + EPSV); sa = inv; sb = bv[j] - mv[j] * inv; }
    ws[OFF_BNA + d] = sa;
    ws[OFF_BNB + d] = sb;
  }
  int i = d * 256 + c;
  // MFMA A-operand (weights) fragment table: wtab[chunk][lane] = 4 dwords = 8 bf16
  // chunk<28: u=chunk/7, t=chunk%7, dh=2t+(quad>>1); chunk 28/29: u=(chunk-28)*2+(quad>>1), dh=14
  // dw = (quad&1)*8 + j, zero weight for dw>=15
  if (i < 7680) {
    int chunk = i >> 8, rem = i & 255, lane = rem >> 2, dp = rem & 3;
    int quad = lane >> 4, k = lane & 15;
    int u, dh;
    if (chunk < 28) { u = chunk / 7; int t = chunk % 7; dh = 2 * t + (quad >> 1); }
    else            { u = (chunk - 28) * 2 + (quad >> 1); dh = 14; }
    int dwb = (quad & 1) * 8 + dp * 2;
    float w0 = (dwb     < 15) ? pos_w[k * 900 + u * 225 + dh * 15 + dwb]     : 0.0f;
    float w1 = (dwb + 1 < 15) ? pos_w[k * 900 + u * 225 + dh * 15 + dwb + 1] : 0.0f;
    ((uint32_t*)(ws + OFF_WT))[i] = f2bf(w0) | (f2bf(w1) << 16);
  }
  if (d < 64) ws[OFF_LC + i] = 0.0f;
}

// ---------------- stage 1: QKV projection GEMM + BN ---------------------------
__launch_bounds__(256, 2)
__global__ void qkv_gemm(const float* __restrict__ x, const float* __restrict__ wsc,
                         float* __restrict__ Y) {
  __shared__ float As[64 * 33];
  __shared__ float Xs[32 * 64];
  const float* A   = wsc + OFF_A;
  const float* bnA = wsc + OFF_BNA;
  const float* bnB = wsc + OFF_BNB;
  int t  = threadIdx.x;
  int n0 = blockIdx.x * 64, d0 = blockIdx.y * 64, b = blockIdx.z;
  int td = t >> 4, tn = t & 15;
  float acc[4][4];
#pragma unroll
  for (int i = 0; i < 4; ++i)
#pragma unroll
    for (int j = 0; j < 4; ++j) acc[i][j] = 0.0f;
  const size_t xbase = (size_t)b * NC * NPIX;
  for (int kt = 0; kt < 8; ++kt) {
    int k0 = kt * 32;
    const float* ag = A + (d0 + (t >> 2)) * 256 + k0 + (t & 3) * 8;
    float4 a0 = *(const float4*)(ag);
    float4 a1 = *(const float4*)(ag + 4);
    const float* xg = x + xbase + (size_t)(k0 + (t >> 3)) * NPIX + n0 + (t & 7) * 8;
    float4 b0 = *(const float4*)(xg);
    float4 b1 = *(const float4*)(xg + 4);
    float* ap = As + (t >> 2) * 33 + (t & 3) * 8;
    ap[0] = a0.x; ap[1] = a0.y; ap[2] = a0.z; ap[3] = a0.w;
    ap[4] = a1.x; ap[5] = a1.y; ap[6] = a1.z; ap[7] = a1.w;
    *(float4*)(Xs + (t >> 3) * 64 + (t & 7) * 8)     = b0;
    *(float4*)(Xs + (t >> 3) * 64 + (t & 7) * 8 + 4) = b1;
    __syncthreads();
#pragma unroll 8
    for (int kk = 0; kk < 32; ++kk) {
      float av[4];
#pragma unroll
      for (int i = 0; i < 4; ++i) av[i] = As[(td * 4 + i) * 33 + kk];
      float4 xv = *(const float4*)(Xs + kk * 64 + tn * 4);
#pragma unroll
      for (int i = 0; i < 4; ++i) {
        acc[i][0] = fmaf(av[i], xv.x, acc[i][0]);
        acc[i][1] = fmaf(av[i], xv.y, acc[i][1]);
        acc[i][2] = fmaf(av[i], xv.z, acc[i][2]);
        acc[i][3] = fmaf(av[i], xv.w, acc[i][3]);
      }
    }
    __syncthreads();
  }
  if (blockIdx.y == 0) {
    // q tile (d 0..63): apply BN and write bf16 pairs into qb region
    // qb dword index (per b): ((h*4+kq)*2+jp)*NPIX + pix, pairs over k
    uint32_t* qb = (uint32_t*)(Y + (size_t)b * 384 * NPIX);
    float bnv[4][4];
#pragma unroll
    for (int i = 0; i < 4; ++i) {
      int d = td * 4 + i;
      float sa = bnA[d], sb = bnB[d];
#pragma unroll
      for (int j = 0; j < 4; ++j) bnv[i][j] = fmaf(acc[i][j], sa, sb);
    }
    int dbase = td * 4;
    int h = dbase >> 4, kq = (dbase >> 2) & 3;
#pragma unroll
    for (int pr = 0; pr < 2; ++pr) {
      int base = ((h * 4 + kq) * 2 + pr) * NPIX + n0 + tn * 4;
#pragma unroll
      for (int j = 0; j < 4; ++j)
        qb[base + j] = f2bf(bnv[2 * pr][j]) | (f2bf(bnv[2 * pr + 1][j]) << 16);
    }
  } else {
#pragma unroll
    for (int i = 0; i < 4; ++i) {
      int d = d0 + td * 4 + i;
      float sa = bnA[d], sb = bnB[d];
      float4 o;
      o.x = fmaf(acc[i][0], sa, sb);
      o.y = fmaf(acc[i][1], sa, sb);
      o.z = fmaf(acc[i][2], sa, sb);
      o.w = fmaf(acc[i][3], sa, sb);
      *(float4*)(Y + ((size_t)b * 384 + d) * NPIX + n0 + tn * 4) = o;
    }
  }
}

// ---------------- stage 2: softmax over positions for k rows ------------------
__global__ void softmax_k(float* __restrict__ Y) {
  int row = blockIdx.x;
  int b = row >> 6, r = row & 63;
  float* p = Y + ((size_t)b * 384 + 64 + r) * NPIX;
  int t = threadIdx.x;
  __shared__ float red[8];
  float m = -3.4e38f;
  for (int n = t; n < NPIX; n += 256) m = fmaxf(m, p[n]);
#pragma unroll
  for (int off = 32; off; off >>= 1) m = fmaxf(m, __shfl_xor(m, off, 64));
  if ((t & 63) == 0) red[t >> 6] = m;
  __syncthreads();
  if (t == 0) red[0] = fmaxf(fmaxf(red[0], red[1]), fmaxf(red[2], red[3]));
  __syncthreads();
  m = red[0];
  float s = 0.0f;
  for (int n = t; n < NPIX; n += 256) { float e = __expf(p[n] - m); p[n] = e; s += e; }
#pragma unroll
  for (int off = 32; off; off >>= 1) s += __shfl_xor(s, off, 64);
  if ((t & 63) == 0) red[4 + (t >> 6)] = s;
  __syncthreads();
  if (t == 0) red[4] = red[4] + red[5] + red[6] + red[7];
  __syncthreads();
  float inv = 1.0f / red[4];
  for (int n = t; n < NPIX; n += 256) p[n] *= inv;
}

// ---------------- stage 3: Lc[b][k][v] ----------------------------------------
__global__ void lc_kernel(const float* __restrict__ Y, float* __restrict__ ws) {
  int v = blockIdx.x, u = blockIdx.y, b = blockIdx.z;
  float* Lc = ws + OFF_LC;
  const float* krows = Y + ((size_t)b * 384 + 64 + u * 16) * NPIX;
  const float* vrow  = Y + ((size_t)b * 384 + 128 + u * 64 + v) * NPIX;
  float acc[16];
#pragma unroll
  for (int k = 0; k < 16; ++k) acc[k] = 0.0f;
  for (int n = threadIdx.x; n < NPIX; n += 256) {
    float vv = vrow[n];
#pragma unroll
    for (int k = 0; k < 16; ++k) acc[k] = fmaf(krows[(size_t)k * NPIX + n], vv, acc[k]);
  }
#pragma unroll
  for (int k = 0; k < 16; ++k) {
    float a = acc[k];
#pragma unroll
    for (int off = 32; off; off >>= 1) a += __shfl_xor(a, off, 64);
    if ((threadIdx.x & 63) == 0) atomicAdd(&Lc[(b * 16 + k) * 64 + v], a);
  }
}

// ---------------- stage 4: MFMA position conv + fused output contraction ------
// D[k=16][pix=16] per wave via mfma 16x16x32 bf16; K = (u, dh, dw) im2col.
// LDS: padded v rows, dual copies (shift 0 / shift 1) so every B-fragment is
// 4 consecutive 4B-aligned dwords (2x ds_read2_b32, no fixup).
#define RSTR   72      // dwords per padded row: copyA 36 + copyB 36
#define UPITCH 3312    // 46 rows * RSTR
#define LDSW   13248   // 4 u-planes

__launch_bounds__(512, 2)
__global__ void pos_lambda_mfma(const float* __restrict__ Y, const float* __restrict__ wsc,
                                const float* __restrict__ pos_b, float* __restrict__ out) {
  __shared__ uint32_t S[LDSW];
  int v = blockIdx.x, b = blockIdx.y, band = blockIdx.z;
  int rb = band * 32;
  int tid = threadIdx.x;
  // ---- stage padded v planes (bf16 dual-copy) ----
  for (int i = tid; i < LDSW; i += 512) {
    int u = i / UPITCH; int rem = i - u * UPITCH;
    int pr = rem / RSTR; int dc = rem - pr * RSTR;
    int cp = dc >= 36; int j = dc - cp * 36;
    int e0 = 2 * j + cp;                 // padded-row element index (0..70), e1 = e0+1
    int gr = rb + pr - 7;
    float f0 = 0.0f, f1 = 0.0f;
    if (gr >= 0 && gr < NW) {
      const float* vp = Y + ((size_t)(b * 384 + 128 + u * 64 + v)) * NPIX + gr * NW;
      int gc0 = e0 - 7, gc1 = e0 - 6;
      if (gc0 >= 0 && gc0 < NW) f0 = vp[gc0];
      if (gc1 >= 0 && gc1 < NW) f1 = vp[gc1];
    }
    S[i] = f2bf(f0) | (f2bf(f1) << 16);
  }
  int lane = tid & 63, wid = tid >> 6;
  int quad = lane >> 4, n = lane & 15;
  int dhp = quad >> 1;
  // ---- preload weight fragments (30 chunks x 4 VGPR) ----
  bf16x8 wf[30];
  {
    const uint4* wt = (const uint4*)(wsc + OFF_WT);
#pragma unroll
    for (int c = 0; c < 30; ++c) {
      union { uint4 q; bf16x8 v; } tmp;
      tmp.q = wt[c * 64 + lane];
      wf[c] = tmp.v;
    }
  }
  float lcq[4];
#pragma unroll
  for (int r = 0; r < 4; ++r) {
    int k = quad * 4 + r;
    lcq[r] = wsc[OFF_LC + (b * 16 + k) * 64 + v] + pos_b[k];
  }
  __syncthreads();
  const uint32_t* qb = (const uint32_t*)(Y + (size_t)b * 384 * NPIX);
  int ntasks = band ? 24 : 32;
  for (int task = wid; task < ntasks; task += 8) {
    int ct = task & 3, rg = task >> 2;
    int r0 = (rg >> 1) * 8 + (rg & 1);        // local row base; rows r0,r0+2,r0+4,r0+6
    int cb = (ct << 4) - ((ct >> 1) & (ct << 3));  // {0,16,32,40}
    cb = (ct == 3) ? 40 : ct * 16;
    int sb = cb + n + (quad & 1) * 8;
    int P = sb & 1;
    int coldw = (P ? 36 : 0) + ((sb - P) >> 1);
    f32x4 acc[4] = {{0,0,0,0},{0,0,0,0},{0,0,0,0},{0,0,0,0}};
#pragma unroll
    for (int u = 0; u < 4; ++u) {
      int base = u * UPITCH + dhp * RSTR + coldw;
#pragma unroll
      for (int PP = 0; PP < 10; ++PP) {
        int a = base + (r0 + 2 * PP) * RSTR;
        uint32_t d0 = S[a], d1 = S[a + 1], d2 = S[a + 2], d3 = S[a + 3];
        union { uint32_t u4[4]; bf16x8 v8; } bu;
        bu.u4[0] = d0; bu.u4[1] = d1; bu.u4[2] = d2; bu.u4[3] = d3;
#pragma unroll
        for (int q = 0; q < 4; ++q) {
          if (q >= (PP > 6 ? PP - 6 : 0) && q <= (PP < 3 ? PP : 3))
            acc[q] = __builtin_amdgcn_mfma_f32_16x16x32_bf16(wf[u * 7 + (PP - q)], bu.v8, acc[q], 0, 0, 0);
        }
      }
    }
    // leftover dh = 14 (two chunks pack u-pairs)
#pragma unroll
    for (int q = 0; q < 4; ++q) {
      int prow = r0 + 2 * q + 14;
#pragma unroll
      for (int up = 0; up < 2; ++up) {
        int a = (up * 2 + dhp) * UPITCH + prow * RSTR + coldw;
        uint32_t d0 = S[a], d1 = S[a + 1], d2 = S[a + 2], d3 = S[a + 3];
        union { uint32_t u4[4]; bf16x8 v8; } bu;
        bu.u4[0] = d0; bu.u4[1] = d1; bu.u4[2] = d2; bu.u4[3] = d3;
        acc[q] = __builtin_amdgcn_mfma_f32_16x16x32_bf16(wf[28 + up], bu.v8, acc[q], 0, 0, 0);
      }
    }
    // ---- fused epilogue: y[h] = sum_k q[h,k,n] * (Lp + Lc + pos_b) ----
#pragma unroll
    for (int q = 0; q < 4; ++q) {
      int rr = rb + r0 + 2 * q;
      int pix = rr * NW + cb + n;
      float m0 = acc[q][0] + lcq[0], m1 = acc[q][1] + lcq[1];
      float m2 = acc[q][2] + lcq[2], m3 = acc[q][3] + lcq[3];
      float y[4];
#pragma unroll
      for (int h = 0; h < 4; ++h) {
        uint32_t qd0 = qb[((h * 4 + quad) * 2 + 0) * NPIX + pix];
        uint32_t qd1 = qb[((h * 4 + quad) * 2 + 1) * NPIX + pix];
        float q0 = __uint_as_float(qd0 << 16);
        float q1 = __uint_as_float(qd0 & 0xffff0000u);
        float q2 = __uint_as_float(qd1 << 16);
        float q3 = __uint_as_float(qd1 & 0xffff0000u);
        float s = fmaf(q0, m0, fmaf(q1, m1, fmaf(q2, m2, q3 * m3)));
        s += __shfl_xor(s, 16);
        s += __shfl_xor(s, 32);
        y[h] = s;
      }
      out[((size_t)(b * 256 + quad * 64 + v)) * NPIX + pix] = y[quad];
    }
  }
}

extern "C" void kernel_launch(void* const* d_in, const int* in_sizes, int n_in,
                              void* d_out, int out_size, void* d_ws, size_t ws_size,
                              hipStream_t stream) {
  const float* x     = (const float*)d_in[0];
  const float* Wq    = (const float*)d_in[1];
  const float* Wk    = (const float*)d_in[2];
  const float* Wv    = (const float*)d_in[3];
  const float* pos_w = (const float*)d_in[4];
  const float* pos_b = (const float*)d_in[5];
  const float* gq    = (const float*)d_in[6];
  const float* bq    = (const float*)d_in[7];
  const float* mq    = (const float*)d_in[8];
  const float* vq    = (const float*)d_in[9];
  const float* gv    = (const float*)d_in[10];
  const float* bv    = (const float*)d_in[11];
  const float* mv    = (const float*)d_in[12];
  const float* vv    = (const float*)d_in[13];
  float* ws  = (float*)d_ws;
  float* out = (float*)d_out;
  float* Y   = ws + OFF_Y;

  prep_kernel<<<dim3(384), 256, 0, stream>>>(Wq, Wk, Wv, pos_w, gq, bq, mq, vq,
                                             gv, bv, mv, vv, ws);
  qkv_gemm<<<dim3(49, 6, 16), 256, 0, stream>>>(x, ws, Y);
  softmax_k<<<dim3(1024), 256, 0, stream>>>(Y);
  lc_kernel<<<dim3(64, 4, 16), 256, 0, stream>>>(Y, ws);
  pos_lambda_mfma<<<dim3(64, 16, 2), 512, 0, stream>>>(Y, ws, pos_b, out);
}

// Round 3
// 458.064 us; speedup vs baseline: 2.6057x; 1.2000x over previous
//
#include <hip/hip_runtime.h>
#include <cstdint>
#include <cstddef>

#define NB   16
#define NC   256
#define NPIX 3136
#define NW   56
#define EPSV 1e-5f

// ws layout in floats
#define OFF_A    0u        // A[384][256]
#define OFF_BNA  98304u    // [384]
#define OFF_BNB  98688u    // [384]
#define OFF_WT   99072u    // wtab: 32 chunks x 64 lanes x 4 dwords = 8192 dwords
#define OFF_LC   107264u   // Lc[16][16][64]
#define OFF_Y    123648u   // Y[16][384][3136]; rows 0..31 reused as qb2 (uint2 bf16 pairs)

typedef short bf16x8 __attribute__((ext_vector_type(8)));
typedef float f32x4  __attribute__((ext_vector_type(4)));

__device__ __forceinline__ uint32_t f2bf(float f) {
  uint32_t x = __float_as_uint(f);
  uint32_t r = x + 0x7fffu + ((x >> 16) & 1u);
  return r >> 16;
}

// ---------------- prep: build A, BN coeffs, MFMA weight fragments, zero Lc ----
__global__ void prep_kernel(const float* __restrict__ Wq, const float* __restrict__ Wk,
                            const float* __restrict__ Wv, const float* __restrict__ pos_w,
                            const float* __restrict__ gq, const float* __restrict__ bq,
                            const float* __restrict__ mq, const float* __restrict__ vq,
                            const float* __restrict__ gv, const float* __restrict__ bv,
                            const float* __restrict__ mv, const float* __restrict__ vv,
                            float* __restrict__ ws) {
  int d = blockIdx.x;    // 0..383
  int c = threadIdx.x;   // 0..255
  float w;
  if (d < 64)        w = Wq[c * 64 + d];
  else if (d < 128)  w = Wk[c * 64 + (d - 64)];
  else               w = Wv[c * 256 + (d - 128)];
  ws[OFF_A + d * 256 + c] = w;
  if (c == 0) {
    float sa, sb;
    if (d < 64)        { float inv = gq[d] / sqrtf(vq[d] + EPSV); sa = inv; sb = bq[d] - mq[d] * inv; }
    else if (d < 128)  { sa = 1.0f; sb = 0.0f; }
    else               { int j = d - 128; float inv = gv[j] / sqrtf(vv[j] + EPSV); sa = inv; sb = bv[j] - mv[j] * inv; }
    ws[OFF_BNA + d] = sa;
    ws[OFF_BNB + d] = sb;
  }
  int i = d * 256 + c;
  // wtab[chunk = u*8+t][lane][dp]: dh = 2t + (quad>>1), dw = (quad&1)*8 + dp*2 + {0,1}
  // zero weight for dh>14 or dw>14
  if (i < 8192) {
    int chunk = i >> 8, rem = i & 255, lane = rem >> 2, dp = rem & 3;
    int quad = lane >> 4, k = lane & 15;
    int u = chunk >> 3, t = chunk & 7;
    int dh = 2 * t + (quad >> 1);
    int dwb = (quad & 1) * 8 + dp * 2;
    float w0 = (dh < 15 && dwb     < 15) ? pos_w[k * 900 + u * 225 + dh * 15 + dwb]     : 0.0f;
    float w1 = (dh < 15 && dwb + 1 < 15) ? pos_w[k * 900 + u * 225 + dh * 15 + dwb + 1] : 0.0f;
    ((uint32_t*)(ws + OFF_WT))[i] = f2bf(w0) | (f2bf(w1) << 16);
  }
  if (d < 64) ws[OFF_LC + i] = 0.0f;
}

// ---------------- stage 1: QKV projection GEMM + BN ---------------------------
__launch_bounds__(256, 2)
__global__ void qkv_gemm(const float* __restrict__ x, const float* __restrict__ wsc,
                         float* __restrict__ Y) {
  __shared__ float As[64 * 33];
  __shared__ float Xs[32 * 64];
  const float* A   = wsc + OFF_A;
  const float* bnA = wsc + OFF_BNA;
  const float* bnB = wsc + OFF_BNB;
  int t  = threadIdx.x;
  int n0 = blockIdx.x * 64, d0 = blockIdx.y * 64, b = blockIdx.z;
  int td = t >> 4, tn = t & 15;
  float acc[4][4];
#pragma unroll
  for (int i = 0; i < 4; ++i)
#pragma unroll
    for (int j = 0; j < 4; ++j) acc[i][j] = 0.0f;
  const size_t xbase = (size_t)b * NC * NPIX;
  for (int kt = 0; kt < 8; ++kt) {
    int k0 = kt * 32;
    const float* ag = A + (d0 + (t >> 2)) * 256 + k0 + (t & 3) * 8;
    float4 a0 = *(const float4*)(ag);
    float4 a1 = *(const float4*)(ag + 4);
    const float* xg = x + xbase + (size_t)(k0 + (t >> 3)) * NPIX + n0 + (t & 7) * 8;
    float4 b0 = *(const float4*)(xg);
    float4 b1 = *(const float4*)(xg + 4);
    float* ap = As + (t >> 2) * 33 + (t & 3) * 8;
    ap[0] = a0.x; ap[1] = a0.y; ap[2] = a0.z; ap[3] = a0.w;
    ap[4] = a1.x; ap[5] = a1.y; ap[6] = a1.z; ap[7] = a1.w;
    *(float4*)(Xs + (t >> 3) * 64 + (t & 7) * 8)     = b0;
    *(float4*)(Xs + (t >> 3) * 64 + (t & 7) * 8 + 4) = b1;
    __syncthreads();
#pragma unroll 8
    for (int kk = 0; kk < 32; ++kk) {
      float av[4];
#pragma unroll
      for (int i = 0; i < 4; ++i) av[i] = As[(td * 4 + i) * 33 + kk];
      float4 xv = *(const float4*)(Xs + kk * 64 + tn * 4);
#pragma unroll
      for (int i = 0; i < 4; ++i) {
        acc[i][0] = fmaf(av[i], xv.x, acc[i][0]);
        acc[i][1] = fmaf(av[i], xv.y, acc[i][1]);
        acc[i][2] = fmaf(av[i], xv.z, acc[i][2]);
        acc[i][3] = fmaf(av[i], xv.w, acc[i][3]);
      }
    }
    __syncthreads();
  }
  if (blockIdx.y == 0) {
    // q tile (d 0..63): BN then bf16-pair pack: qb2[(h*4+kq)*NPIX + pix] = uint2
    // .x = (k=kq*4+0, kq*4+1), .y = (k=kq*4+2, kq*4+3)
    uint2* qb2 = (uint2*)(Y + (size_t)b * 384 * NPIX);
    float bnv[4][4];
#pragma unroll
    for (int i = 0; i < 4; ++i) {
      int d = td * 4 + i;
      float sa = bnA[d], sb = bnB[d];
#pragma unroll
      for (int j = 0; j < 4; ++j) bnv[i][j] = fmaf(acc[i][j], sa, sb);
    }
    int base = td * NPIX + n0 + tn * 4;
#pragma unroll
    for (int j = 0; j < 4; ++j) {
      uint2 val;
      val.x = f2bf(bnv[0][j]) | (f2bf(bnv[1][j]) << 16);
      val.y = f2bf(bnv[2][j]) | (f2bf(bnv[3][j]) << 16);
      qb2[base + j] = val;
    }
  } else {
#pragma unroll
    for (int i = 0; i < 4; ++i) {
      int d = d0 + td * 4 + i;
      float sa = bnA[d], sb = bnB[d];
      float4 o;
      o.x = fmaf(acc[i][0], sa, sb);
      o.y = fmaf(acc[i][1], sa, sb);
      o.z = fmaf(acc[i][2], sa, sb);
      o.w = fmaf(acc[i][3], sa, sb);
      *(float4*)(Y + ((size_t)b * 384 + d) * NPIX + n0 + tn * 4) = o;
    }
  }
}

// ---------------- stage 2: softmax over positions for k rows ------------------
__global__ void softmax_k(float* __restrict__ Y) {
  int row = blockIdx.x;
  int b = row >> 6, r = row & 63;
  float* p = Y + ((size_t)b * 384 + 64 + r) * NPIX;
  int t = threadIdx.x;
  __shared__ float red[8];
  float m = -3.4e38f;
  for (int n = t; n < NPIX; n += 256) m = fmaxf(m, p[n]);
#pragma unroll
  for (int off = 32; off; off >>= 1) m = fmaxf(m, __shfl_xor(m, off, 64));
  if ((t & 63) == 0) red[t >> 6] = m;
  __syncthreads();
  if (t == 0) red[0] = fmaxf(fmaxf(red[0], red[1]), fmaxf(red[2], red[3]));
  __syncthreads();
  m = red[0];
  float s = 0.0f;
  for (int n = t; n < NPIX; n += 256) { float e = __expf(p[n] - m); p[n] = e; s += e; }
#pragma unroll
  for (int off = 32; off; off >>= 1) s += __shfl_xor(s, off, 64);
  if ((t & 63) == 0) red[4 + (t >> 6)] = s;
  __syncthreads();
  if (t == 0) red[4] = red[4] + red[5] + red[6] + red[7];
  __syncthreads();
  float inv = 1.0f / red[4];
  for (int n = t; n < NPIX; n += 256) p[n] *= inv;
}

// ---------------- stage 3: Lc[b][k][v], 4 v per block -------------------------
__global__ void lc_kernel(const float* __restrict__ Y, float* __restrict__ ws) {
  int vg = blockIdx.x, u = blockIdx.y, b = blockIdx.z;   // v = vg*4 + vi
  float* Lc = ws + OFF_LC;
  const float* krows = Y + ((size_t)b * 384 + 64 + u * 16) * NPIX;
  const float* vrows = Y + ((size_t)b * 384 + 128 + u * 64 + vg * 4) * NPIX;
  float acc[16][4];
#pragma unroll
  for (int k = 0; k < 16; ++k)
#pragma unroll
    for (int vi = 0; vi < 4; ++vi) acc[k][vi] = 0.0f;
  for (int n = threadIdx.x; n < NPIX; n += 256) {
    float vv[4];
#pragma unroll
    for (int vi = 0; vi < 4; ++vi) vv[vi] = vrows[(size_t)vi * NPIX + n];
#pragma unroll
    for (int k = 0; k < 16; ++k) {
      float kk = krows[(size_t)k * NPIX + n];
#pragma unroll
      for (int vi = 0; vi < 4; ++vi) acc[k][vi] = fmaf(kk, vv[vi], acc[k][vi]);
    }
  }
#pragma unroll
  for (int k = 0; k < 16; ++k)
#pragma unroll
    for (int vi = 0; vi < 4; ++vi) {
      float a = acc[k][vi];
#pragma unroll
      for (int off = 32; off; off >>= 1) a += __shfl_xor(a, off, 64);
      if ((threadIdx.x & 63) == 0) atomicAdd(&Lc[(b * 16 + k) * 64 + vg * 4 + vi], a);
    }
}

// ---------------- stage 4: MFMA position conv + fused output contraction ------
// Per wave: Q=7 output rows (stride 2, parity p) x 16 cols. K padded to (u, 8 dh-chunks).
// LDS: interleaved bf16-pair layout: dword at pos holds elems (pos, pos+1);
// fragment = dwords {sb, sb+2, sb+4, sb+6} -> 2x ds_read2_b32, ~conflict-free.
#define ROWS   29
#define RSTR2  74
#define UPITCH2 2146   // ROWS * RSTR2
#define LDSW2  8584    // 4 * UPITCH2

__launch_bounds__(512, 4)
__global__ void pos_lambda_mfma(const float* __restrict__ Y, const float* __restrict__ wsc,
                                const float* __restrict__ pos_b, float* __restrict__ out) {
  __shared__ uint32_t S[LDSW2];
  int v = blockIdx.x, b = blockIdx.y, band = blockIdx.z;
  int rb = band * 14;
  int tid = threadIdx.x;
  // ---- stage padded v planes ----
  for (int i = tid; i < LDSW2; i += 512) {
    int u = i / UPITCH2; int rem = i - u * UPITCH2;
    int prow = rem / RSTR2; int pos = rem - prow * RSTR2;
    int gr = rb + prow - 7;
    float f0 = 0.0f, f1 = 0.0f;
    if (gr >= 0 && gr < NW && pos < 72) {
      const float* vp = Y + ((size_t)(b * 384 + 128 + u * 64 + v)) * NPIX + gr * NW;
      int g0 = pos - 7, g1 = pos - 6;
      if (g0 >= 0 && g0 < NW) f0 = vp[g0];
      if (g1 >= 0 && g1 < NW) f1 = vp[g1];
    }
    S[i] = f2bf(f0) | (f2bf(f1) << 16);
  }
  __syncthreads();
  int lane = tid & 63, wid = tid >> 6;
  int quad = lane >> 4, n = lane & 15;
  int dhp = quad >> 1;
  int ct = wid & 3, p = wid >> 2;
  int cb = (ct == 3) ? 40 : ct * 16;
  int sb = cb + n + (quad & 1) * 8;
  int abase = (p + dhp) * RSTR2 + sb;
  const uint4* wt = (const uint4*)(wsc + OFF_WT);
  f32x4 acc[7];
#pragma unroll
  for (int q = 0; q < 7; ++q) acc[q] = (f32x4){0.f, 0.f, 0.f, 0.f};
#pragma unroll 1
  for (int u = 0; u < 4; ++u) {
    bf16x8 wf[8];
#pragma unroll
    for (int t = 0; t < 8; ++t) {
      union { uint4 q; bf16x8 v; } tmp;
      tmp.q = wt[(u * 8 + t) * 64 + lane];
      wf[t] = tmp.v;
    }
    int au = u * UPITCH2 + abase;
#pragma unroll
    for (int PP = 0; PP < 14; ++PP) {
      int a = au + PP * (2 * RSTR2);
      union { uint32_t u4[4]; bf16x8 v8; } bu;
      bu.u4[0] = S[a];     bu.u4[1] = S[a + 2];
      bu.u4[2] = S[a + 4]; bu.u4[3] = S[a + 6];
#pragma unroll
      for (int t = 0; t < 8; ++t) {
        int q = PP - t;
        if (q >= 0 && q < 7)
          acc[q] = __builtin_amdgcn_mfma_f32_16x16x32_bf16(wf[t], bu.v8, acc[q], 0, 0, 0);
      }
    }
  }
  // ---- fused epilogue ----
  float lcq[4];
#pragma unroll
  for (int r = 0; r < 4; ++r) {
    int k = quad * 4 + r;
    lcq[r] = wsc[OFF_LC + (b * 16 + k) * 64 + v] + pos_b[k];
  }
  const uint2* qb2 = (const uint2*)(Y + (size_t)b * 384 * NPIX);
#pragma unroll
  for (int q = 0; q < 7; ++q) {
    int rr = rb + p + 2 * q;
    int pix = rr * NW + cb + n;
    float m0 = acc[q][0] + lcq[0], m1 = acc[q][1] + lcq[1];
    float m2 = acc[q][2] + lcq[2], m3 = acc[q][3] + lcq[3];
    float yq = 0.0f;
#pragma unroll
    for (int h = 0; h < 4; ++h) {
      uint2 qd = qb2[(h * 4 + quad) * NPIX + pix];
      float q0 = __uint_as_float(qd.x << 16);
      float q1 = __uint_as_float(qd.x & 0xffff0000u);
      float q2 = __uint_as_float(qd.y << 16);
      float q3 = __uint_as_float(qd.y & 0xffff0000u);
      float s = fmaf(q0, m0, fmaf(q1, m1, fmaf(q2, m2, q3 * m3)));
      s += __shfl_xor(s, 16);
      s += __shfl_xor(s, 32);
      if (h == quad) yq = s;
    }
    out[((size_t)(b * 256 + quad * 64 + v)) * NPIX + pix] = yq;
  }
}

extern "C" void kernel_launch(void* const* d_in, const int* in_sizes, int n_in,
                              void* d_out, int out_size, void* d_ws, size_t ws_size,
                              hipStream_t stream) {
  const float* x     = (const float*)d_in[0];
  const float* Wq    = (const float*)d_in[1];
  const float* Wk    = (const float*)d_in[2];
  const float* Wv    = (const float*)d_in[3];
  const float* pos_w = (const float*)d_in[4];
  const float* pos_b = (const float*)d_in[5];
  const float* gq    = (const float*)d_in[6];
  const float* bq    = (const float*)d_in[7];
  const float* mq    = (const float*)d_in[8];
  const float* vq    = (const float*)d_in[9];
  const float* gv    = (const float*)d_in[10];
  const float* bv    = (const float*)d_in[11];
  const float* mv    = (const float*)d_in[12];
  const float* vv    = (const float*)d_in[13];
  float* ws  = (float*)d_ws;
  float* out = (float*)d_out;
  float* Y   = ws + OFF_Y;

  prep_kernel<<<dim3(384), 256, 0, stream>>>(Wq, Wk, Wv, pos_w, gq, bq, mq, vq,
                                             gv, bv, mv, vv, ws);
  qkv_gemm<<<dim3(49, 6, 16), 256, 0, stream>>>(x, ws, Y);
  softmax_k<<<dim3(1024), 256, 0, stream>>>(Y);
  lc_kernel<<<dim3(16, 4, 16), 256, 0, stream>>>(Y, ws);
  pos_lambda_mfma<<<dim3(64, 16, 4), 512, 0, stream>>>(Y, ws, pos_b, out);
}

// Round 4
// 331.167 us; speedup vs baseline: 3.6041x; 1.3832x over previous
//
#include <hip/hip_runtime.h>
#include <cstdint>
#include <cstddef>

#define NB   16
#define NC   256
#define NPIX 3136
#define NW   56
#define EPSV 1e-5f

// ws layout in dwords/floats
#define OFF_AB   0u        // Abf: 12 dtiles x 16 kchunks x 64 lanes x 4 dw = 49152
#define OFF_BNA  49152u    // [384] (BNB contiguous after)
#define OFF_BNB  49536u    // [384]
#define OFF_WT   49920u    // wtab: 32 chunks x 64 lanes x 4 dw = 8192
#define OFF_LC   58112u    // Lc[16][16][64] = 16384
#define OFF_Y    74496u    // Y[16][384][3136]; per-b dwords 0..32*NPIX = qb2 (uint2 bf16 pairs)

typedef short bf16x8 __attribute__((ext_vector_type(8)));
typedef float f32x4  __attribute__((ext_vector_type(4)));
typedef float f32x16 __attribute__((ext_vector_type(16)));

__device__ __forceinline__ uint32_t f2bf(float f) {
  uint32_t x = __float_as_uint(f);
  uint32_t r = x + 0x7fffu + ((x >> 16) & 1u);
  return r >> 16;
}

__device__ __forceinline__ float fetchW(const float* Wq, const float* Wk,
                                        const float* Wv, int m, int c) {
  if (m < 64)  return Wq[c * 64 + m];
  if (m < 128) return Wk[c * 64 + (m - 64)];
  return Wv[c * 256 + (m - 128)];
}

// ---------------- prep: bf16 A-fragments, BN coeffs, pos-w fragments, zero Lc -
__global__ void prep_kernel(const float* __restrict__ Wq, const float* __restrict__ Wk,
                            const float* __restrict__ Wv, const float* __restrict__ pos_w,
                            const float* __restrict__ gq, const float* __restrict__ bq,
                            const float* __restrict__ mq, const float* __restrict__ vq,
                            const float* __restrict__ gv, const float* __restrict__ bv,
                            const float* __restrict__ mv, const float* __restrict__ vv,
                            float* __restrict__ ws) {
  int d = blockIdx.x;    // 0..383
  int c = threadIdx.x;   // 0..255
  int i = d * 256 + c;
  // A fragment table for mfma_32x32x16_bf16:
  // Abf[dgt][kc][lane] 4 dw = 8 bf16: A[m][k], m = dgt*32+(lane&31),
  // k = kc*16 + (lane>>5)*8 + dp*2 + {0,1}
  if (i < 49152) {
    int dgt = i >> 12, rem = i & 4095;
    int kc = rem >> 8, rem2 = rem & 255;
    int lane = rem2 >> 2, dp = rem2 & 3;
    int m = dgt * 32 + (lane & 31);
    int k0 = kc * 16 + (lane >> 5) * 8 + dp * 2;
    float w0 = fetchW(Wq, Wk, Wv, m, k0);
    float w1 = fetchW(Wq, Wk, Wv, m, k0 + 1);
    ((uint32_t*)(ws + OFF_AB))[i] = f2bf(w0) | (f2bf(w1) << 16);
  }
  if (c == 0) {
    float sa, sb;
    if (d < 64)        { float inv = gq[d] / sqrtf(vq[d] + EPSV); sa = inv; sb = bq[d] - mq[d] * inv; }
    else if (d < 128)  { sa = 1.0f; sb = 0.0f; }
    else               { int j = d - 128; float inv = gv[j] / sqrtf(vv[j] + EPSV); sa = inv; sb = bv[j] - mv[j] * inv; }
    ws[OFF_BNA + d] = sa;
    ws[OFF_BNB + d] = sb;
  }
  // pos-w fragment table (16x16x32 path in pos_lambda)
  if (i < 8192) {
    int chunk = i >> 8, rem = i & 255, lane = rem >> 2, dp = rem & 3;
    int quad = lane >> 4, k = lane & 15;
    int u = chunk >> 3, t = chunk & 7;
    int dh = 2 * t + (quad >> 1);
    int dwb = (quad & 1) * 8 + dp * 2;
    float w0 = (dh < 15 && dwb     < 15) ? pos_w[k * 900 + u * 225 + dh * 15 + dwb]     : 0.0f;
    float w1 = (dh < 15 && dwb + 1 < 15) ? pos_w[k * 900 + u * 225 + dh * 15 + dwb + 1] : 0.0f;
    ((uint32_t*)(ws + OFF_WT))[i] = f2bf(w0) | (f2bf(w1) << 16);
  }
  if (d < 64) ws[OFF_LC + i] = 0.0f;
}

// ---------------- stage 1: QKV projection via MFMA 32x32x16 bf16 --------------
// Block: 384d x 64n, full K=256 staged once. Wave w: d in [w*96, w*96+96).
// LDS X: bf16 k-pair dwords, row n (stride 128 dw), XOR-granule swizzle.
__launch_bounds__(256, 2)
__global__ void qkv_mfma(const float* __restrict__ x, const float* __restrict__ wsc,
                         float* __restrict__ Y) {
  __shared__ uint32_t X[64 * 128];   // 32 KB
  __shared__ float BNs[768];
  int tid = threadIdx.x;
  int n0 = blockIdx.x * 64, b = blockIdx.y;
  for (int i = tid; i < 768; i += 256) BNs[i] = wsc[OFF_BNA + i];
  const size_t xb = (size_t)b * NC * NPIX;
  // ---- stage x tile [256c x 64n] -> bf16 pairs ----
#pragma unroll
  for (int it = 0; it < 4; ++it) {
    int n2 = tid & 31;
    int cp4 = it * 8 + (tid >> 5);
    const float* xp = x + xb + (size_t)(cp4 * 8) * NPIX + n0 + n2 * 2;
    float2 ld[8];
#pragma unroll
    for (int j = 0; j < 8; ++j) ld[j] = *(const float2*)(xp + (size_t)j * NPIX);
    uint32_t e0, e1, e2, e3, o0, o1, o2, o3;
    e0 = f2bf(ld[0].x) | (f2bf(ld[1].x) << 16);
    e1 = f2bf(ld[2].x) | (f2bf(ld[3].x) << 16);
    e2 = f2bf(ld[4].x) | (f2bf(ld[5].x) << 16);
    e3 = f2bf(ld[6].x) | (f2bf(ld[7].x) << 16);
    o0 = f2bf(ld[0].y) | (f2bf(ld[1].y) << 16);
    o1 = f2bf(ld[2].y) | (f2bf(ld[3].y) << 16);
    o2 = f2bf(ld[4].y) | (f2bf(ld[5].y) << 16);
    o3 = f2bf(ld[6].y) | (f2bf(ld[7].y) << 16);
    int ne = 2 * n2, no = ne + 1;
    uint4 ve; ve.x = e0; ve.y = e1; ve.z = e2; ve.w = e3;
    uint4 vo; vo.x = o0; vo.y = o1; vo.z = o2; vo.w = o3;
    *(uint4*)(X + ne * 128 + ((cp4 ^ (ne & 31)) << 2)) = ve;
    *(uint4*)(X + no * 128 + ((cp4 ^ (no & 31)) << 2)) = vo;
  }
  __syncthreads();
  int lane = tid & 63, w = tid >> 6;
  int n31 = lane & 31, h5 = lane >> 5;
  f32x16 acc[3][2];
#pragma unroll
  for (int dt = 0; dt < 3; ++dt)
#pragma unroll
    for (int nt = 0; nt < 2; ++nt)
#pragma unroll
      for (int e = 0; e < 16; ++e) acc[dt][nt][e] = 0.0f;
  const uint4* AB = (const uint4*)(wsc + OFF_AB);
#pragma unroll 4
  for (int kc = 0; kc < 16; ++kc) {
    bf16x8 af[3];
#pragma unroll
    for (int dt = 0; dt < 3; ++dt) {
      union { uint4 q; bf16x8 v; } tmp;
      tmp.q = AB[(size_t)(((w * 3 + dt) * 16 + kc)) * 64 + lane];
      af[dt] = tmp.v;
    }
#pragma unroll
    for (int nt = 0; nt < 2; ++nt) {
      union { uint4 q; bf16x8 v; } bu;
      bu.q = *(const uint4*)(X + (nt * 32 + n31) * 128 + (((2 * kc + h5) ^ n31) << 2));
#pragma unroll
      for (int dt = 0; dt < 3; ++dt)
        acc[dt][nt] = __builtin_amdgcn_mfma_f32_32x32x16_bf16(af[dt], bu.v, acc[dt][nt], 0, 0, 0);
    }
  }
  // ---- epilogue: BN + store (q packed bf16 pairs, k/v fp32) ----
#pragma unroll
  for (int dt = 0; dt < 3; ++dt) {
    int dgt = w * 3 + dt;
    float sa[16], sb[16];
#pragma unroll
    for (int g = 0; g < 4; ++g) {
      *(float4*)(sa + g * 4) = *(const float4*)(BNs + dgt * 32 + g * 8 + h5 * 4);
      *(float4*)(sb + g * 4) = *(const float4*)(BNs + 384 + dgt * 32 + g * 8 + h5 * 4);
    }
#pragma unroll
    for (int nt = 0; nt < 2; ++nt) {
      int pix = n0 + nt * 32 + n31;
      if (dgt < 2) {
        uint2* qb2 = (uint2*)(Y + (size_t)b * 384 * NPIX);
#pragma unroll
        for (int g = 0; g < 4; ++g) {
          float y0 = fmaf(acc[dt][nt][4 * g + 0], sa[4 * g + 0], sb[4 * g + 0]);
          float y1 = fmaf(acc[dt][nt][4 * g + 1], sa[4 * g + 1], sb[4 * g + 1]);
          float y2 = fmaf(acc[dt][nt][4 * g + 2], sa[4 * g + 2], sb[4 * g + 2]);
          float y3 = fmaf(acc[dt][nt][4 * g + 3], sa[4 * g + 3], sb[4 * g + 3]);
          uint2 val;
          val.x = f2bf(y0) | (f2bf(y1) << 16);
          val.y = f2bf(y2) | (f2bf(y3) << 16);
          qb2[(size_t)(dgt * 8 + 2 * g + h5) * NPIX + pix] = val;
        }
      } else {
#pragma unroll
        for (int g = 0; g < 4; ++g)
#pragma unroll
          for (int ki = 0; ki < 4; ++ki) {
            int d = dgt * 32 + 8 * g + 4 * h5 + ki;
            Y[((size_t)b * 384 + d) * NPIX + pix] =
                fmaf(acc[dt][nt][4 * g + ki], sa[4 * g + ki], sb[4 * g + ki]);
          }
      }
    }
  }
}

// ---------------- stage 2: softmax over positions for k rows ------------------
__global__ void softmax_k(float* __restrict__ Y) {
  int row = blockIdx.x;
  int b = row >> 6, r = row & 63;
  float* p = Y + ((size_t)b * 384 + 64 + r) * NPIX;
  int t = threadIdx.x;
  __shared__ float red[8];
  float m = -3.4e38f;
  for (int n = t; n < NPIX; n += 256) m = fmaxf(m, p[n]);
#pragma unroll
  for (int off = 32; off; off >>= 1) m = fmaxf(m, __shfl_xor(m, off, 64));
  if ((t & 63) == 0) red[t >> 6] = m;
  __syncthreads();
  if (t == 0) red[0] = fmaxf(fmaxf(red[0], red[1]), fmaxf(red[2], red[3]));
  __syncthreads();
  m = red[0];
  float s = 0.0f;
  for (int n = t; n < NPIX; n += 256) { float e = __expf(p[n] - m); p[n] = e; s += e; }
#pragma unroll
  for (int off = 32; off; off >>= 1) s += __shfl_xor(s, off, 64);
  if ((t & 63) == 0) red[4 + (t >> 6)] = s;
  __syncthreads();
  if (t == 0) red[4] = red[4] + red[5] + red[6] + red[7];
  __syncthreads();
  float inv = 1.0f / red[4];
  for (int n = t; n < NPIX; n += 256) p[n] *= inv;
}

// ---------------- stage 3: Lc[b][k][v], 4 v per block -------------------------
__global__ void lc_kernel(const float* __restrict__ Y, float* __restrict__ ws) {
  int vg = blockIdx.x, u = blockIdx.y, b = blockIdx.z;   // v = vg*4 + vi
  float* Lc = ws + OFF_LC;
  const float* krows = Y + ((size_t)b * 384 + 64 + u * 16) * NPIX;
  const float* vrows = Y + ((size_t)b * 384 + 128 + u * 64 + vg * 4) * NPIX;
  float acc[16][4];
#pragma unroll
  for (int k = 0; k < 16; ++k)
#pragma unroll
    for (int vi = 0; vi < 4; ++vi) acc[k][vi] = 0.0f;
  for (int n = threadIdx.x; n < NPIX; n += 256) {
    float vv[4];
#pragma unroll
    for (int vi = 0; vi < 4; ++vi) vv[vi] = vrows[(size_t)vi * NPIX + n];
#pragma unroll
    for (int k = 0; k < 16; ++k) {
      float kk = krows[(size_t)k * NPIX + n];
#pragma unroll
      for (int vi = 0; vi < 4; ++vi) acc[k][vi] = fmaf(kk, vv[vi], acc[k][vi]);
    }
  }
#pragma unroll
  for (int k = 0; k < 16; ++k)
#pragma unroll
    for (int vi = 0; vi < 4; ++vi) {
      float a = acc[k][vi];
#pragma unroll
      for (int off = 32; off; off >>= 1) a += __shfl_xor(a, off, 64);
      if ((threadIdx.x & 63) == 0) atomicAdd(&Lc[(b * 16 + k) * 64 + vg * 4 + vi], a);
    }
}

// ---------------- stage 4: MFMA position conv + fused output contraction ------
#define ROWS   29
#define RSTR2  74
#define UPITCH2 2146   // ROWS * RSTR2
#define LDSW2  8584    // 4 * UPITCH2

__launch_bounds__(512, 4)
__global__ void pos_lambda_mfma(const float* __restrict__ Y, const float* __restrict__ wsc,
                                const float* __restrict__ pos_b, float* __restrict__ out) {
  __shared__ uint32_t S[LDSW2];
  int v = blockIdx.x, b = blockIdx.y, band = blockIdx.z;
  int rb = band * 14;
  int tid = threadIdx.x;
  for (int i = tid; i < LDSW2; i += 512) {
    int u = i / UPITCH2; int rem = i - u * UPITCH2;
    int prow = rem / RSTR2; int pos = rem - prow * RSTR2;
    int gr = rb + prow - 7;
    float f0 = 0.0f, f1 = 0.0f;
    if (gr >= 0 && gr < NW && pos < 72) {
      const float* vp = Y + ((size_t)(b * 384 + 128 + u * 64 + v)) * NPIX + gr * NW;
      int g0 = pos - 7, g1 = pos - 6;
      if (g0 >= 0 && g0 < NW) f0 = vp[g0];
      if (g1 >= 0 && g1 < NW) f1 = vp[g1];
    }
    S[i] = f2bf(f0) | (f2bf(f1) << 16);
  }
  __syncthreads();
  int lane = tid & 63, wid = tid >> 6;
  int quad = lane >> 4, n = lane & 15;
  int dhp = quad >> 1;
  int ct = wid & 3, p = wid >> 2;
  int cb = (ct == 3) ? 40 : ct * 16;
  int sb = cb + n + (quad & 1) * 8;
  int abase = (p + dhp) * RSTR2 + sb;
  const uint4* wt = (const uint4*)(wsc + OFF_WT);
  f32x4 acc[7];
#pragma unroll
  for (int q = 0; q < 7; ++q) acc[q] = (f32x4){0.f, 0.f, 0.f, 0.f};
#pragma unroll 1
  for (int u = 0; u < 4; ++u) {
    bf16x8 wf[8];
#pragma unroll
    for (int t = 0; t < 8; ++t) {
      union { uint4 q; bf16x8 v; } tmp;
      tmp.q = wt[(u * 8 + t) * 64 + lane];
      wf[t] = tmp.v;
    }
    int au = u * UPITCH2 + abase;
#pragma unroll
    for (int PP = 0; PP < 14; ++PP) {
      int a = au + PP * (2 * RSTR2);
      union { uint32_t u4[4]; bf16x8 v8; } bu;
      bu.u4[0] = S[a];     bu.u4[1] = S[a + 2];
      bu.u4[2] = S[a + 4]; bu.u4[3] = S[a + 6];
#pragma unroll
      for (int t = 0; t < 8; ++t) {
        int q = PP - t;
        if (q >= 0 && q < 7)
          acc[q] = __builtin_amdgcn_mfma_f32_16x16x32_bf16(wf[t], bu.v8, acc[q], 0, 0, 0);
      }
    }
  }
  float lcq[4];
#pragma unroll
  for (int r = 0; r < 4; ++r) {
    int k = quad * 4 + r;
    lcq[r] = wsc[OFF_LC + (b * 16 + k) * 64 + v] + pos_b[k];
  }
  const uint2* qb2 = (const uint2*)(Y + (size_t)b * 384 * NPIX);
#pragma unroll
  for (int q = 0; q < 7; ++q) {
    int rr = rb + p + 2 * q;
    int pix = rr * NW + cb + n;
    float m0 = acc[q][0] + lcq[0], m1 = acc[q][1] + lcq[1];
    float m2 = acc[q][2] + lcq[2], m3 = acc[q][3] + lcq[3];
    float yq = 0.0f;
#pragma unroll
    for (int h = 0; h < 4; ++h) {
      uint2 qd = qb2[(h * 4 + quad) * NPIX + pix];
      float q0 = __uint_as_float(qd.x << 16);
      float q1 = __uint_as_float(qd.x & 0xffff0000u);
      float q2 = __uint_as_float(qd.y << 16);
      float q3 = __uint_as_float(qd.y & 0xffff0000u);
      float s = fmaf(q0, m0, fmaf(q1, m1, fmaf(q2, m2, q3 * m3)));
      s += __shfl_xor(s, 16);
      s += __shfl_xor(s, 32);
      if (h == quad) yq = s;
    }
    out[((size_t)(b * 256 + quad * 64 + v)) * NPIX + pix] = yq;
  }
}

extern "C" void kernel_launch(void* const* d_in, const int* in_sizes, int n_in,
                              void* d_out, int out_size, void* d_ws, size_t ws_size,
                              hipStream_t stream) {
  const float* x     = (const float*)d_in[0];
  const float* Wq    = (const float*)d_in[1];
  const float* Wk    = (const float*)d_in[2];
  const float* Wv    = (const float*)d_in[3];
  const float* pos_w = (const float*)d_in[4];
  const float* pos_b = (const float*)d_in[5];
  const float* gq    = (const float*)d_in[6];
  const float* bq    = (const float*)d_in[7];
  const float* mq    = (const float*)d_in[8];
  const float* vq    = (const float*)d_in[9];
  const float* gv    = (const float*)d_in[10];
  const float* bv    = (const float*)d_in[11];
  const float* mv    = (const float*)d_in[12];
  const float* vv    = (const float*)d_in[13];
  float* ws  = (float*)d_ws;
  float* out = (float*)d_out;
  float* Y   = ws + OFF_Y;

  prep_kernel<<<dim3(384), 256, 0, stream>>>(Wq, Wk, Wv, pos_w, gq, bq, mq, vq,
                                             gv, bv, mv, vv, ws);
  qkv_mfma<<<dim3(49, 16), 256, 0, stream>>>(x, ws, Y);
  softmax_k<<<dim3(1024), 256, 0, stream>>>(Y);
  lc_kernel<<<dim3(16, 4, 16), 256, 0, stream>>>(Y, ws);
  pos_lambda_mfma<<<dim3(64, 16, 4), 512, 0, stream>>>(Y, ws, pos_b, out);
}